// Round 12
// baseline (333.477 us; speedup 1.0000x reference)
//
#include <hip/hip_runtime.h>
#include <hip/hip_bf16.h>
#include <hip/hip_fp16.h>
#include <type_traits>

#define Nn 50000
#define RR 3
#define EE 300000

typedef __attribute__((ext_vector_type(8))) short short8;
typedef __attribute__((ext_vector_type(4))) short short4v;
typedef __attribute__((ext_vector_type(4))) float floatx4;

__device__ __forceinline__ short f2bf(float f) {
    __hip_bfloat16 h = __float2bfloat16(f);
    return *reinterpret_cast<short*>(&h);
}

// ---------------- count (8 edges/thread, ordinal out) + fused W pre-swizzle ----------------
// blocks [0, 440): count; blocks [440, 488): wswz. counts pre-zeroed by hipMemsetAsync.

__global__ void count_wswz_kernel(const int* __restrict__ edges, int* __restrict__ counts,
                                  int* __restrict__ ord,
                                  const float* __restrict__ W1, const float* __restrict__ W2,
                                  short* __restrict__ Z) {
    int bx = blockIdx.x;
    if (bx >= 440) {
        int idx = (bx - 440) * 256 + threadIdx.x;   // 2*3*4*8*64 = 12288
        if (idx >= 12288) return;
        int lane = idx & 63;
        int nt = (idx >> 6) & 7;
        int kt = (idx >> 9) & 3;
        int rl = idx >> 11;
        int layer = rl / 3, r = rl % 3;
        const float* W = (layer ? W2 : W1) + (size_t)r * 16384;
        int n = nt * 16 + (lane & 15);
        int k0 = kt * 32 + (lane >> 4) * 8;
        short8 v;
        #pragma unroll
        for (int j = 0; j < 8; ++j) v[j] = f2bf(W[(size_t)(k0 + j) * 128 + n]);
        *(short8*)&Z[(size_t)idx * 8] = v;
        return;
    }
    int i = bx * 256 + threadIdx.x;   // RR*EE/8 threads
    if (i >= RR * EE / 8) return;
    int g = i * 8;
    int r = g / EE, e0 = g - r * EE;
    const int* db = &edges[(size_t)r * 2 * EE + EE + e0];
    int4 d0 = *(const int4*)db;
    int4 d1 = *(const int4*)(db + 4);
    int* cb = counts + r * Nn;
    int4 o0, o1;
    o0.x = atomicAdd(&cb[d0.x], 1);
    o0.y = atomicAdd(&cb[d0.y], 1);
    o0.z = atomicAdd(&cb[d0.z], 1);
    o0.w = atomicAdd(&cb[d0.w], 1);
    o1.x = atomicAdd(&cb[d1.x], 1);
    o1.y = atomicAdd(&cb[d1.y], 1);
    o1.z = atomicAdd(&cb[d1.z], 1);
    o1.w = atomicAdd(&cb[d1.w], 1);
    *(int4*)&ord[g] = o0;
    *(int4*)&ord[g + 4] = o1;
}

__global__ __launch_bounds__(256) void alloc_kernel(const int* __restrict__ counts,
                                                    int* __restrict__ row_start,
                                                    int* __restrict__ totals) {
    __shared__ int s[256];
    __shared__ int base_s;
    int r = blockIdx.y;
    int tid = threadIdx.x;
    int n = blockIdx.x * 256 + tid;
    int idx = r * Nn + n;
    int c = (n < Nn) ? counts[idx] : 0;
    s[tid] = c;
    __syncthreads();
    #pragma unroll
    for (int off = 1; off < 256; off <<= 1) {
        int v = 0;
        if (tid >= off) v = s[tid - off];
        __syncthreads();
        if (tid >= off) s[tid] += v;
        __syncthreads();
    }
    if (tid == 255) base_s = atomicAdd(&totals[r], s[255]);
    __syncthreads();
    if (n < Nn) row_start[idx] = base_s + s[tid] - c;
}

// No atomics: slot = row_start[dst] + ord[edge]; 8 edges/thread; single int2 store per
// edge (one cache line touched per edge, not two -> halves write-allocate traffic).
__global__ void scatter_kernel(const int* __restrict__ edges, const int* __restrict__ ord,
                               const int* __restrict__ row_start, int2* __restrict__ csr) {
    int i = blockIdx.x * blockDim.x + threadIdx.x;
    if (i >= RR * EE / 8) return;
    int g = i * 8;
    int r = g / EE, e0 = g - r * EE;
    const int* sb = &edges[(size_t)r * 2 * EE + e0];
    const int* db = sb + EE;
    int4 s0 = *(const int4*)sb, s1 = *(const int4*)(sb + 4);
    int4 d0 = *(const int4*)db, d1 = *(const int4*)(db + 4);
    int4 o0 = *(const int4*)&ord[g], o1 = *(const int4*)&ord[g + 4];
    const int* rs = row_start + r * Nn;
    int2* cb = csr + (size_t)r * EE;
    cb[rs[d0.x] + o0.x] = make_int2(s0.x, d0.x);
    cb[rs[d0.y] + o0.y] = make_int2(s0.y, d0.y);
    cb[rs[d0.z] + o0.z] = make_int2(s0.z, d0.z);
    cb[rs[d0.w] + o0.w] = make_int2(s0.w, d0.w);
    cb[rs[d1.x] + o1.x] = make_int2(s1.x, d1.x);
    cb[rs[d1.y] + o1.y] = make_int2(s1.y, d1.y);
    cb[rs[d1.z] + o1.z] = make_int2(s1.z, d1.z);
    cb[rs[d1.w] + o1.w] = make_int2(s1.w, d1.w);
}

// ---------------- MFMA GEMM + fused el/er epilogue ----------------
// TA = float (layer 1) or short (layer 2, bf16 relu-applied).

template<typename TA>
__global__ __launch_bounds__(256) void gemm_proj_mfma(const TA* __restrict__ A,
                                                      const short* __restrict__ Z,
                                                      const float* __restrict__ al,
                                                      const float* __restrict__ ar,
                                                      __half* __restrict__ C,
                                                      float* __restrict__ el,
                                                      float* __restrict__ er) {
    __shared__ short A_lds[64 * 136];   // reused as __half[64*136] for the epilogue
    __shared__ float al_lds[384], ar_lds[384];
    int tid = threadIdx.x;
    int row0 = blockIdx.x * 64;
    if (tid < 128) { al_lds[256 + tid] = al[256 + tid]; ar_lds[256 + tid] = ar[256 + tid]; }
    al_lds[tid] = al[tid]; ar_lds[tid] = ar[tid];
    if constexpr (std::is_same<TA, float>::value) {
        #pragma unroll
        for (int p = 0; p < 8; ++p) {
            int f = p * 256 + tid;
            int row = f >> 5;
            int c4 = (f & 31) * 4;
            float4 v = make_float4(0.f, 0.f, 0.f, 0.f);
            if (row0 + row < Nn) v = *(const float4*)&A[(size_t)(row0 + row) * 128 + c4];
            short4v sv;
            sv[0] = f2bf(v.x); sv[1] = f2bf(v.y); sv[2] = f2bf(v.z); sv[3] = f2bf(v.w);
            *(short4v*)&A_lds[row * 136 + c4] = sv;
        }
    } else {
        #pragma unroll
        for (int p = 0; p < 4; ++p) {
            int c = p * 256 + tid;          // 1024 chunks of 8 shorts
            int row = c >> 4, c8 = (c & 15) * 8;
            short8 v = (short8)(0);
            if (row0 + row < Nn) v = *(const short8*)&A[(size_t)(row0 + row) * 128 + c8];
            *(short8*)&A_lds[row * 136 + c8] = v;
        }
    }
    __syncthreads();
    int wave = tid >> 6, lane = tid & 63;
    int m = lane & 15, q = lane >> 4;
    short8 af[4];
    #pragma unroll
    for (int kt = 0; kt < 4; ++kt)
        af[kt] = *(short8*)&A_lds[(wave * 16 + m) * 136 + kt * 32 + q * 8];
    __syncthreads();   // A_lds dead; reuse as epilogue buffer
    __half* lds_h = (__half*)A_lds;
    int row8 = tid >> 2;
    int hh = tid & 3;
    for (int r = 0; r < RR; ++r) {
        floatx4 acc[8];
        #pragma unroll
        for (int nt = 0; nt < 8; ++nt) acc[nt] = (floatx4)(0.f);
        const short* Zr = Z + (size_t)r * 16384;
        #pragma unroll
        for (int kt = 0; kt < 4; ++kt) {
            #pragma unroll
            for (int nt = 0; nt < 8; ++nt) {
                short8 bf = *(const short8*)&Zr[(size_t)(kt * 8 + nt) * 512 + lane * 8];
                acc[nt] = __builtin_amdgcn_mfma_f32_16x16x32_bf16(af[kt], bf, acc[nt], 0, 0, 0);
            }
        }
        #pragma unroll
        for (int nt = 0; nt < 8; ++nt) {
            int col = nt * 16 + m;
            #pragma unroll
            for (int reg = 0; reg < 4; ++reg)
                lds_h[(wave * 16 + q * 4 + reg) * 136 + col] = __float2half(acc[nt][reg]);
        }
        __syncthreads();
        __half* Cr = C + (size_t)r * Nn * 128;
        #pragma unroll
        for (int p = 0; p < 4; ++p) {
            int lin = p * 256 + tid;
            int row = lin >> 4, c8 = (lin & 15) * 8;
            if (row0 + row < Nn)
                *(short8*)&Cr[(size_t)(row0 + row) * 128 + c8] = *(short8*)&lds_h[row * 136 + c8];
        }
        {
            const __half2* fp = (const __half2*)&lds_h[row8 * 136 + hh * 32];
            const float* alp = &al_lds[r * 128 + hh * 32];
            const float* arp = &ar_lds[r * 128 + hh * 32];
            float sl = 0.f, sr = 0.f;
            #pragma unroll
            for (int d = 0; d < 16; ++d) {
                float2 v = __half22float2(fp[d]);
                sl += v.x * alp[2 * d] + v.y * alp[2 * d + 1];
                sr += v.x * arp[2 * d] + v.y * arp[2 * d + 1];
            }
            if (row0 + row8 < Nn) {
                size_t ei = (size_t)(r * Nn + row0 + row8) * 4 + hh;
                el[ei] = sl;
                er[ei] = sr;
            }
        }
        __syncthreads();
    }
}

// ---------------- Final GEMM: A[N,128] @ Wl[128,64] + bl -> out [N,64] fp32 ----------------

__global__ __launch_bounds__(256) void gemm_final_kernel(const float* __restrict__ A,
                                                         const float* __restrict__ Wl,
                                                         const float* __restrict__ bl,
                                                         float* __restrict__ out) {
    __shared__ float As[16][65];
    __shared__ float Bs[16][65];
    int tid = threadIdx.x;
    int row0 = blockIdx.x * 64;
    float acc[4][4] = {};
    int tx = tid & 15, ty = tid >> 4;
    for (int k0 = 0; k0 < 128; k0 += 16) {
        {
            int mm = tid >> 2, c = (tid & 3) * 4;
            int row = row0 + mm;
            float4 v = make_float4(0.f, 0.f, 0.f, 0.f);
            if (row < Nn) v = *(const float4*)&A[(size_t)row * 128 + k0 + c];
            As[c + 0][mm] = v.x; As[c + 1][mm] = v.y; As[c + 2][mm] = v.z; As[c + 3][mm] = v.w;
        }
        {
            int kk = tid >> 4, j = (tid & 15) * 4;
            float4 v = *(const float4*)&Wl[(size_t)(k0 + kk) * 64 + j];
            *(float4*)&Bs[kk][j] = v;
        }
        __syncthreads();
        #pragma unroll
        for (int kk = 0; kk < 16; ++kk) {
            float4 a = *(const float4*)&As[kk][ty * 4];
            float4 b = *(const float4*)&Bs[kk][tx * 4];
            float av[4] = {a.x, a.y, a.z, a.w};
            float bv[4] = {b.x, b.y, b.z, b.w};
            #pragma unroll
            for (int i = 0; i < 4; ++i)
                #pragma unroll
                for (int j = 0; j < 4; ++j) acc[i][j] += av[i] * bv[j];
        }
        __syncthreads();
    }
    float4 bias = *(const float4*)&bl[tx * 4];
    #pragma unroll
    for (int i = 0; i < 4; ++i) {
        int row = row0 + ty * 4 + i;
        if (row >= Nn) continue;
        float4 v = make_float4(acc[i][0] + bias.x, acc[i][1] + bias.y,
                               acc[i][2] + bias.z, acc[i][3] + bias.w);
        *(float4*)&out[(size_t)row * 64 + tx * 4] = v;
    }
}

// ---------------- edge-parallel softmax weights, PACKED (src:16 | w:fp16) ----------------
// Nn = 50000 < 2^16, so src fits the low half; agg then needs ONE load + ONE shuffle per edge.

__global__ __launch_bounds__(256) void wexp_kernel(const int2* __restrict__ csr,
                                                   const float* __restrict__ el,
                                                   const float* __restrict__ er,
                                                   unsigned* __restrict__ wqp) {
    int r = blockIdx.y;
    int k = blockIdx.x * 256 + threadIdx.x;
    if (k >= EE) return;
    size_t gk = (size_t)r * EE + k;
    int2 e = csr[gk];
    float4 l4 = *(const float4*)&el[(size_t)(r * Nn + e.x) * 4];
    float4 r4 = *(const float4*)&er[(size_t)(r * Nn + e.y) * 4];
    float lv[4] = {l4.x, l4.y, l4.z, l4.w};
    float rv[4] = {r4.x, r4.y, r4.z, r4.w};
    unsigned sbits = (unsigned)e.x;
    #pragma unroll
    for (int h = 0; h < 4; ++h) {
        float x = lv[h] + rv[h];
        x = (x > 0.f) ? x : 0.2f * x;
        unsigned wb = (unsigned)__half_as_ushort(__float2half(__expf(x)));
        wqp[(size_t)h * (RR * EE) + gk] = sbits | (wb << 16);
    }
}

// ---------------- aggregation: one wave per dst node; packed single-shuffle edges ----------------

template<bool OUT_BF16_RELU>
__global__ __launch_bounds__(256) void agg_kernel(const __half2* __restrict__ feat2,
                                                  const unsigned* __restrict__ wqp,
                                                  const int* __restrict__ row_start,
                                                  const int* __restrict__ counts,
                                                  const float* __restrict__ b,
                                                  void* __restrict__ out) {
    int wave = threadIdx.x >> 6;
    int lane = threadIdx.x & 63;
    int n = blockIdx.x * 4 + wave;
    if (n >= Nn) return;
    int h = lane >> 4;
    int hl = lane & 15;
    int grp = lane & 48;
    int t2 = lane * 2;
    int cntA[RR], stA[RR];
    unsigned pC[RR];
    #pragma unroll
    for (int r = 0; r < RR; ++r) {
        cntA[r] = counts[r * Nn + n];
        stA[r] = row_start[r * Nn + n];
    }
    #pragma unroll
    for (int r = 0; r < RR; ++r) {
        pC[r] = 0u;
        if (hl < cntA[r])
            pC[r] = wqp[(size_t)h * (RR * EE) + (size_t)r * EE + stA[r] + hl];
    }
    float accx = b[t2] + b[128 + t2] + b[256 + t2];
    float accy = b[t2 + 1] + b[128 + t2 + 1] + b[256 + t2 + 1];
    #pragma unroll
    for (int r = 0; r < RR; ++r) {
        int cnt = cntA[r];
        if (cnt == 0) continue;
        const __half2* fr = feat2 + (size_t)r * Nn * 64;
        float den = 0.f, numx = 0.f, numy = 0.f;
        unsigned p_l = pC[r];
        int i0 = 0;
        while (true) {
            int mm = cnt - i0; if (mm > 16) mm = 16;
            int mm8 = (mm + 7) & ~7;
            for (int j = 0; j < mm8; j += 8) {
                unsigned u0 = __shfl(p_l, grp | j);
                unsigned u1 = __shfl(p_l, grp | (j + 1));
                unsigned u2 = __shfl(p_l, grp | (j + 2));
                unsigned u3 = __shfl(p_l, grp | (j + 3));
                unsigned u4 = __shfl(p_l, grp | (j + 4));
                unsigned u5 = __shfl(p_l, grp | (j + 5));
                unsigned u6 = __shfl(p_l, grp | (j + 6));
                unsigned u7 = __shfl(p_l, grp | (j + 7));
                __half2 f0 = fr[(size_t)(u0 & 0xFFFFu) * 64 + lane];
                __half2 f1 = fr[(size_t)(u1 & 0xFFFFu) * 64 + lane];
                __half2 f2 = fr[(size_t)(u2 & 0xFFFFu) * 64 + lane];
                __half2 f3 = fr[(size_t)(u3 & 0xFFFFu) * 64 + lane];
                __half2 f4 = fr[(size_t)(u4 & 0xFFFFu) * 64 + lane];
                __half2 f5 = fr[(size_t)(u5 & 0xFFFFu) * 64 + lane];
                __half2 f6 = fr[(size_t)(u6 & 0xFFFFu) * 64 + lane];
                __half2 f7 = fr[(size_t)(u7 & 0xFFFFu) * 64 + lane];
                float w0 = __half2float(__ushort_as_half((unsigned short)(u0 >> 16)));
                float w1 = __half2float(__ushort_as_half((unsigned short)(u1 >> 16)));
                float w2 = __half2float(__ushort_as_half((unsigned short)(u2 >> 16)));
                float w3 = __half2float(__ushort_as_half((unsigned short)(u3 >> 16)));
                float w4 = __half2float(__ushort_as_half((unsigned short)(u4 >> 16)));
                float w5 = __half2float(__ushort_as_half((unsigned short)(u5 >> 16)));
                float w6 = __half2float(__ushort_as_half((unsigned short)(u6 >> 16)));
                float w7 = __half2float(__ushort_as_half((unsigned short)(u7 >> 16)));
                float2 g0 = __half22float2(f0), g1 = __half22float2(f1);
                float2 g2 = __half22float2(f2), g3 = __half22float2(f3);
                float2 g4 = __half22float2(f4), g5 = __half22float2(f5);
                float2 g6 = __half22float2(f6), g7 = __half22float2(f7);
                den += ((w0 + w1) + (w2 + w3)) + ((w4 + w5) + (w6 + w7));
                numx += (w0 * g0.x + w1 * g1.x + w2 * g2.x + w3 * g3.x)
                      + (w4 * g4.x + w5 * g5.x + w6 * g6.x + w7 * g7.x);
                numy += (w0 * g0.y + w1 * g1.y + w2 * g2.y + w3 * g3.y)
                      + (w4 * g4.y + w5 * g5.y + w6 * g6.y + w7 * g7.y);
            }
            i0 += 16;
            if (i0 >= cnt) break;
            p_l = 0u;
            if (i0 + hl < cnt)
                p_l = wqp[(size_t)h * (RR * EE) + (size_t)r * EE + stA[r] + i0 + hl];
        }
        float inv = 1.f / den;
        accx += numx * inv;
        accy += numy * inv;
    }
    if constexpr (OUT_BF16_RELU) {
        short* o = (short*)out;
        short2 pk;
        pk.x = f2bf(fmaxf(accx, 0.f));
        pk.y = f2bf(fmaxf(accy, 0.f));
        *(short2*)&o[(size_t)n * 128 + t2] = pk;
    } else {
        float* o = (float*)out;
        *(float2*)&o[(size_t)n * 128 + t2] = make_float2(accx, accy);
    }
}

// ---------------- launch ----------------

extern "C" void kernel_launch(void* const* d_in, const int* in_sizes, int n_in,
                              void* d_out, int out_size, void* d_ws, size_t ws_size,
                              hipStream_t stream) {
    const float* x   = (const float*)d_in[0];
    const int*  edges = (const int*)d_in[1];
    const float* W1  = (const float*)d_in[2];
    const float* al1 = (const float*)d_in[3];
    const float* ar1 = (const float*)d_in[4];
    const float* b1  = (const float*)d_in[5];
    const float* W2  = (const float*)d_in[6];
    const float* al2 = (const float*)d_in[7];
    const float* ar2 = (const float*)d_in[8];
    const float* b2  = (const float*)d_in[9];
    const float* Wl  = (const float*)d_in[10];
    const float* bl  = (const float*)d_in[11];
    float* out = (float*)d_out;

    // workspace layout (~95 MB; ws proven >= 113 MB in R2)
    __half* feat  = (__half*)d_ws;                          // 3*N*128 fp16
    short* Z      = (short*)(feat + (size_t)RR * Nn * 128); // 98304 bf16
    float* el     = (float*)(Z + 98304);                    // 3*N*4
    float* er     = el + (size_t)RR * Nn * 4;               // 3*N*4
    float* outbuf = er + (size_t)RR * Nn * 4;               // N*128 fp32 (l2) / bf16 (l1)
    unsigned* wqp = (unsigned*)(outbuf + (size_t)Nn * 128); // 4 * 3E u32 (src|w packed)
    int* counts    = (int*)(wqp + (size_t)4 * RR * EE);     // 3*N   (contiguous with totals
    int* totals    = counts + RR * Nn;                      // 4      for single memset)
    int* row_start = totals + 4;                            // 3*N
    int* ord       = row_start + RR * Nn;                   // 3*E
    int2* csr      = (int2*)(ord + RR * EE);                // 3*E int2 {src,dst}
    short* outb16  = (short*)outbuf;                        // layer-1 bf16 view

    const int rowBlocks  = (Nn + 63) / 64;    // 782
    const int nodeBlocks = (Nn + 255) / 256;  // 196
    const int aggBlocks  = (Nn + 3) / 4;      // 12500
    const int edgeBlocks = (EE + 255) / 256;  // 1172
    const int edge8Blocks = (RR * EE / 8 + 255) / 256;  // 440

    // CSR build: memset zeroes counts+totals; wswz hides under count
    hipMemsetAsync(counts, 0, (size_t)(RR * Nn + 4) * sizeof(int), stream);
    count_wswz_kernel<<<440 + 48, 256, 0, stream>>>(edges, counts, ord, W1, W2, Z);
    alloc_kernel<<<dim3(nodeBlocks, RR), 256, 0, stream>>>(counts, row_start, totals);
    scatter_kernel<<<edge8Blocks, 256, 0, stream>>>(edges, ord, row_start, csr);

    // layer 1 (el/er fused into gemm epilogue; agg writes bf16+relu)
    gemm_proj_mfma<float><<<rowBlocks, 256, 0, stream>>>(x, Z, al1, ar1, feat, el, er);
    wexp_kernel<<<dim3(edgeBlocks, RR), 256, 0, stream>>>(csr, el, er, wqp);
    agg_kernel<true><<<aggBlocks, 256, 0, stream>>>((const __half2*)feat, wqp, row_start, counts, b1, outb16);

    // layer 2 (bf16 A input, relu already applied)
    gemm_proj_mfma<short><<<rowBlocks, 256, 0, stream>>>(outb16, Z + 49152, al2, ar2, feat, el, er);
    wexp_kernel<<<dim3(edgeBlocks, RR), 256, 0, stream>>>(csr, el, er, wqp);
    agg_kernel<false><<<aggBlocks, 256, 0, stream>>>((const __half2*)feat, wqp, row_start, counts, b2, outbuf);

    // final linear
    gemm_final_kernel<<<rowBlocks, 256, 0, stream>>>(outbuf, Wl, bl, out);
}

// Round 13
// 324.930 us; speedup vs baseline: 1.0263x; 1.0263x over previous
//
#include <hip/hip_runtime.h>
#include <hip/hip_bf16.h>
#include <hip/hip_fp16.h>
#include <type_traits>

#define Nn 50000
#define RR 3
#define EE 300000

typedef __attribute__((ext_vector_type(8))) short short8;
typedef __attribute__((ext_vector_type(4))) short short4v;
typedef __attribute__((ext_vector_type(4))) float floatx4;

__device__ __forceinline__ short f2bf(float f) {
    __hip_bfloat16 h = __float2bfloat16(f);
    return *reinterpret_cast<short*>(&h);
}

// ---------------- count (8 edges/thread, ordinal out) + fused W pre-swizzle ----------------
// blocks [0, 440): count; blocks [440, 488): wswz. counts pre-zeroed by hipMemsetAsync.

__global__ void count_wswz_kernel(const int* __restrict__ edges, int* __restrict__ counts,
                                  int* __restrict__ ord,
                                  const float* __restrict__ W1, const float* __restrict__ W2,
                                  short* __restrict__ Z) {
    int bx = blockIdx.x;
    if (bx >= 440) {
        int idx = (bx - 440) * 256 + threadIdx.x;   // 2*3*4*8*64 = 12288
        if (idx >= 12288) return;
        int lane = idx & 63;
        int nt = (idx >> 6) & 7;
        int kt = (idx >> 9) & 3;
        int rl = idx >> 11;
        int layer = rl / 3, r = rl % 3;
        const float* W = (layer ? W2 : W1) + (size_t)r * 16384;
        int n = nt * 16 + (lane & 15);
        int k0 = kt * 32 + (lane >> 4) * 8;
        short8 v;
        #pragma unroll
        for (int j = 0; j < 8; ++j) v[j] = f2bf(W[(size_t)(k0 + j) * 128 + n]);
        *(short8*)&Z[(size_t)idx * 8] = v;
        return;
    }
    int i = bx * 256 + threadIdx.x;   // RR*EE/8 threads
    if (i >= RR * EE / 8) return;
    int g = i * 8;
    int r = g / EE, e0 = g - r * EE;
    const int* db = &edges[(size_t)r * 2 * EE + EE + e0];
    int4 d0 = *(const int4*)db;
    int4 d1 = *(const int4*)(db + 4);
    int* cb = counts + r * Nn;
    int4 o0, o1;
    o0.x = atomicAdd(&cb[d0.x], 1);
    o0.y = atomicAdd(&cb[d0.y], 1);
    o0.z = atomicAdd(&cb[d0.z], 1);
    o0.w = atomicAdd(&cb[d0.w], 1);
    o1.x = atomicAdd(&cb[d1.x], 1);
    o1.y = atomicAdd(&cb[d1.y], 1);
    o1.z = atomicAdd(&cb[d1.z], 1);
    o1.w = atomicAdd(&cb[d1.w], 1);
    *(int4*)&ord[g] = o0;
    *(int4*)&ord[g + 4] = o1;
}

__global__ __launch_bounds__(256) void alloc_kernel(const int* __restrict__ counts,
                                                    int* __restrict__ row_start,
                                                    int* __restrict__ totals) {
    __shared__ int s[256];
    __shared__ int base_s;
    int r = blockIdx.y;
    int tid = threadIdx.x;
    int n = blockIdx.x * 256 + tid;
    int idx = r * Nn + n;
    int c = (n < Nn) ? counts[idx] : 0;
    s[tid] = c;
    __syncthreads();
    #pragma unroll
    for (int off = 1; off < 256; off <<= 1) {
        int v = 0;
        if (tid >= off) v = s[tid - off];
        __syncthreads();
        if (tid >= off) s[tid] += v;
        __syncthreads();
    }
    if (tid == 255) base_s = atomicAdd(&totals[r], s[255]);
    __syncthreads();
    if (n < Nn) row_start[idx] = base_s + s[tid] - c;
}

// No atomics: slot = row_start[dst] + ord[edge]; 8 edges/thread; src-only plane (4 B/edge —
// agg recomputes w inline and already knows dst=n, so dst is never stored).
__global__ void scatter_kernel(const int* __restrict__ edges, const int* __restrict__ ord,
                               const int* __restrict__ row_start, int* __restrict__ csr_s) {
    int i = blockIdx.x * blockDim.x + threadIdx.x;
    if (i >= RR * EE / 8) return;
    int g = i * 8;
    int r = g / EE, e0 = g - r * EE;
    const int* sb = &edges[(size_t)r * 2 * EE + e0];
    const int* db = sb + EE;
    int4 s0 = *(const int4*)sb, s1 = *(const int4*)(sb + 4);
    int4 d0 = *(const int4*)db, d1 = *(const int4*)(db + 4);
    int4 o0 = *(const int4*)&ord[g], o1 = *(const int4*)&ord[g + 4];
    const int* rs = row_start + r * Nn;
    int* cs = csr_s + (size_t)r * EE;
    cs[rs[d0.x] + o0.x] = s0.x;
    cs[rs[d0.y] + o0.y] = s0.y;
    cs[rs[d0.z] + o0.z] = s0.z;
    cs[rs[d0.w] + o0.w] = s0.w;
    cs[rs[d1.x] + o1.x] = s1.x;
    cs[rs[d1.y] + o1.y] = s1.y;
    cs[rs[d1.z] + o1.z] = s1.z;
    cs[rs[d1.w] + o1.w] = s1.w;
}

// ---------------- MFMA GEMM + fused el/er epilogue ----------------
// TA = float (layer 1) or short (layer 2, bf16 relu-applied).

template<typename TA>
__global__ __launch_bounds__(256) void gemm_proj_mfma(const TA* __restrict__ A,
                                                      const short* __restrict__ Z,
                                                      const float* __restrict__ al,
                                                      const float* __restrict__ ar,
                                                      __half* __restrict__ C,
                                                      float* __restrict__ el,
                                                      float* __restrict__ er) {
    __shared__ short A_lds[64 * 136];   // reused as __half[64*136] for the epilogue
    __shared__ float al_lds[384], ar_lds[384];
    int tid = threadIdx.x;
    int row0 = blockIdx.x * 64;
    if (tid < 128) { al_lds[256 + tid] = al[256 + tid]; ar_lds[256 + tid] = ar[256 + tid]; }
    al_lds[tid] = al[tid]; ar_lds[tid] = ar[tid];
    if constexpr (std::is_same<TA, float>::value) {
        #pragma unroll
        for (int p = 0; p < 8; ++p) {
            int f = p * 256 + tid;
            int row = f >> 5;
            int c4 = (f & 31) * 4;
            float4 v = make_float4(0.f, 0.f, 0.f, 0.f);
            if (row0 + row < Nn) v = *(const float4*)&A[(size_t)(row0 + row) * 128 + c4];
            short4v sv;
            sv[0] = f2bf(v.x); sv[1] = f2bf(v.y); sv[2] = f2bf(v.z); sv[3] = f2bf(v.w);
            *(short4v*)&A_lds[row * 136 + c4] = sv;
        }
    } else {
        #pragma unroll
        for (int p = 0; p < 4; ++p) {
            int c = p * 256 + tid;          // 1024 chunks of 8 shorts
            int row = c >> 4, c8 = (c & 15) * 8;
            short8 v = (short8)(0);
            if (row0 + row < Nn) v = *(const short8*)&A[(size_t)(row0 + row) * 128 + c8];
            *(short8*)&A_lds[row * 136 + c8] = v;
        }
    }
    __syncthreads();
    int wave = tid >> 6, lane = tid & 63;
    int m = lane & 15, q = lane >> 4;
    short8 af[4];
    #pragma unroll
    for (int kt = 0; kt < 4; ++kt)
        af[kt] = *(short8*)&A_lds[(wave * 16 + m) * 136 + kt * 32 + q * 8];
    __syncthreads();   // A_lds dead; reuse as epilogue buffer
    __half* lds_h = (__half*)A_lds;
    int row8 = tid >> 2;
    int hh = tid & 3;
    for (int r = 0; r < RR; ++r) {
        floatx4 acc[8];
        #pragma unroll
        for (int nt = 0; nt < 8; ++nt) acc[nt] = (floatx4)(0.f);
        const short* Zr = Z + (size_t)r * 16384;
        #pragma unroll
        for (int kt = 0; kt < 4; ++kt) {
            #pragma unroll
            for (int nt = 0; nt < 8; ++nt) {
                short8 bf = *(const short8*)&Zr[(size_t)(kt * 8 + nt) * 512 + lane * 8];
                acc[nt] = __builtin_amdgcn_mfma_f32_16x16x32_bf16(af[kt], bf, acc[nt], 0, 0, 0);
            }
        }
        #pragma unroll
        for (int nt = 0; nt < 8; ++nt) {
            int col = nt * 16 + m;
            #pragma unroll
            for (int reg = 0; reg < 4; ++reg)
                lds_h[(wave * 16 + q * 4 + reg) * 136 + col] = __float2half(acc[nt][reg]);
        }
        __syncthreads();
        __half* Cr = C + (size_t)r * Nn * 128;
        #pragma unroll
        for (int p = 0; p < 4; ++p) {
            int lin = p * 256 + tid;
            int row = lin >> 4, c8 = (lin & 15) * 8;
            if (row0 + row < Nn)
                *(short8*)&Cr[(size_t)(row0 + row) * 128 + c8] = *(short8*)&lds_h[row * 136 + c8];
        }
        {
            const __half2* fp = (const __half2*)&lds_h[row8 * 136 + hh * 32];
            const float* alp = &al_lds[r * 128 + hh * 32];
            const float* arp = &ar_lds[r * 128 + hh * 32];
            float sl = 0.f, sr = 0.f;
            #pragma unroll
            for (int d = 0; d < 16; ++d) {
                float2 v = __half22float2(fp[d]);
                sl += v.x * alp[2 * d] + v.y * alp[2 * d + 1];
                sr += v.x * arp[2 * d] + v.y * arp[2 * d + 1];
            }
            if (row0 + row8 < Nn) {
                size_t ei = (size_t)(r * Nn + row0 + row8) * 4 + hh;
                el[ei] = sl;
                er[ei] = sr;
            }
        }
        __syncthreads();
    }
}

// ---------------- Final GEMM: A[N,128] @ Wl[128,64] + bl -> out [N,64] fp32 ----------------

__global__ __launch_bounds__(256) void gemm_final_kernel(const float* __restrict__ A,
                                                         const float* __restrict__ Wl,
                                                         const float* __restrict__ bl,
                                                         float* __restrict__ out) {
    __shared__ float As[16][65];
    __shared__ float Bs[16][65];
    int tid = threadIdx.x;
    int row0 = blockIdx.x * 64;
    float acc[4][4] = {};
    int tx = tid & 15, ty = tid >> 4;
    for (int k0 = 0; k0 < 128; k0 += 16) {
        {
            int mm = tid >> 2, c = (tid & 3) * 4;
            int row = row0 + mm;
            float4 v = make_float4(0.f, 0.f, 0.f, 0.f);
            if (row < Nn) v = *(const float4*)&A[(size_t)row * 128 + k0 + c];
            As[c + 0][mm] = v.x; As[c + 1][mm] = v.y; As[c + 2][mm] = v.z; As[c + 3][mm] = v.w;
        }
        {
            int kk = tid >> 4, j = (tid & 15) * 4;
            float4 v = *(const float4*)&Wl[(size_t)(k0 + kk) * 64 + j];
            *(float4*)&Bs[kk][j] = v;
        }
        __syncthreads();
        #pragma unroll
        for (int kk = 0; kk < 16; ++kk) {
            float4 a = *(const float4*)&As[kk][ty * 4];
            float4 b = *(const float4*)&Bs[kk][tx * 4];
            float av[4] = {a.x, a.y, a.z, a.w};
            float bv[4] = {b.x, b.y, b.z, b.w};
            #pragma unroll
            for (int i = 0; i < 4; ++i)
                #pragma unroll
                for (int j = 0; j < 4; ++j) acc[i][j] += av[i] * bv[j];
        }
        __syncthreads();
    }
    float4 bias = *(const float4*)&bl[tx * 4];
    #pragma unroll
    for (int i = 0; i < 4; ++i) {
        int row = row0 + ty * 4 + i;
        if (row >= Nn) continue;
        float4 v = make_float4(acc[i][0] + bias.x, acc[i][1] + bias.y,
                               acc[i][2] + bias.z, acc[i][3] + bias.w);
        *(float4*)&out[(size_t)row * 64 + tx * 4] = v;
    }
}

// ---------------- aggregation: one wave per dst node; w computed inline at chunk load ---------
// exp(e)/sum(exp(e)) == softmax (no-max form); |e| <~ 1.5 here so no overflow risk.
// Chunk load (lane hl): src <- csr_s, el gather, w = exp(leaky(el+er)), pack (src | fp16(w)<<16).
// Main loop: 1 shuffle + 1 gather per edge. Amortized inline cost: 1/16 gather + 1/16 exp per edge.

template<bool OUT_BF16_RELU>
__global__ __launch_bounds__(256) void agg_kernel(const __half2* __restrict__ feat2,
                                                  const float* __restrict__ el,
                                                  const float* __restrict__ er,
                                                  const int* __restrict__ csr_s,
                                                  const int* __restrict__ row_start,
                                                  const int* __restrict__ counts,
                                                  const float* __restrict__ b,
                                                  void* __restrict__ out) {
    int wave = threadIdx.x >> 6;
    int lane = threadIdx.x & 63;
    int n = blockIdx.x * 4 + wave;
    if (n >= Nn) return;
    int h = lane >> 4;
    int hl = lane & 15;
    int grp = lane & 48;
    int t2 = lane * 2;
    int cntA[RR], stA[RR], sC[RR];
    #pragma unroll
    for (int r = 0; r < RR; ++r) {
        cntA[r] = counts[r * Nn + n];
        stA[r] = row_start[r * Nn + n];
    }
    #pragma unroll
    for (int r = 0; r < RR; ++r) {
        sC[r] = 0;
        if (hl < cntA[r]) sC[r] = csr_s[(size_t)r * EE + stA[r] + hl];
    }
    float erv[RR];
    #pragma unroll
    for (int r = 0; r < RR; ++r) erv[r] = er[(size_t)(r * Nn + n) * 4 + h];
    unsigned pC[RR];
    #pragma unroll
    for (int r = 0; r < RR; ++r) {
        float x = el[(size_t)(r * Nn + sC[r]) * 4 + h] + erv[r];
        x = (x > 0.f) ? x : 0.2f * x;
        unsigned wb = (hl < cntA[r]) ? (unsigned)__half_as_ushort(__float2half(__expf(x))) : 0u;
        pC[r] = (unsigned)sC[r] | (wb << 16);
    }
    float accx = b[t2] + b[128 + t2] + b[256 + t2];
    float accy = b[t2 + 1] + b[128 + t2 + 1] + b[256 + t2 + 1];
    #pragma unroll
    for (int r = 0; r < RR; ++r) {
        int cnt = cntA[r];
        if (cnt == 0) continue;
        const __half2* fr = feat2 + (size_t)r * Nn * 64;
        float den = 0.f, numx = 0.f, numy = 0.f;
        unsigned p_l = pC[r];
        int i0 = 0;
        while (true) {
            int mm = cnt - i0; if (mm > 16) mm = 16;
            int mm8 = (mm + 7) & ~7;
            for (int j = 0; j < mm8; j += 8) {
                unsigned u0 = __shfl(p_l, grp | j);
                unsigned u1 = __shfl(p_l, grp | (j + 1));
                unsigned u2 = __shfl(p_l, grp | (j + 2));
                unsigned u3 = __shfl(p_l, grp | (j + 3));
                unsigned u4 = __shfl(p_l, grp | (j + 4));
                unsigned u5 = __shfl(p_l, grp | (j + 5));
                unsigned u6 = __shfl(p_l, grp | (j + 6));
                unsigned u7 = __shfl(p_l, grp | (j + 7));
                __half2 f0 = fr[(size_t)(u0 & 0xFFFFu) * 64 + lane];
                __half2 f1 = fr[(size_t)(u1 & 0xFFFFu) * 64 + lane];
                __half2 f2 = fr[(size_t)(u2 & 0xFFFFu) * 64 + lane];
                __half2 f3 = fr[(size_t)(u3 & 0xFFFFu) * 64 + lane];
                __half2 f4 = fr[(size_t)(u4 & 0xFFFFu) * 64 + lane];
                __half2 f5 = fr[(size_t)(u5 & 0xFFFFu) * 64 + lane];
                __half2 f6 = fr[(size_t)(u6 & 0xFFFFu) * 64 + lane];
                __half2 f7 = fr[(size_t)(u7 & 0xFFFFu) * 64 + lane];
                float w0 = __half2float(__ushort_as_half((unsigned short)(u0 >> 16)));
                float w1 = __half2float(__ushort_as_half((unsigned short)(u1 >> 16)));
                float w2 = __half2float(__ushort_as_half((unsigned short)(u2 >> 16)));
                float w3 = __half2float(__ushort_as_half((unsigned short)(u3 >> 16)));
                float w4 = __half2float(__ushort_as_half((unsigned short)(u4 >> 16)));
                float w5 = __half2float(__ushort_as_half((unsigned short)(u5 >> 16)));
                float w6 = __half2float(__ushort_as_half((unsigned short)(u6 >> 16)));
                float w7 = __half2float(__ushort_as_half((unsigned short)(u7 >> 16)));
                float2 g0 = __half22float2(f0), g1 = __half22float2(f1);
                float2 g2 = __half22float2(f2), g3 = __half22float2(f3);
                float2 g4 = __half22float2(f4), g5 = __half22float2(f5);
                float2 g6 = __half22float2(f6), g7 = __half22float2(f7);
                den += ((w0 + w1) + (w2 + w3)) + ((w4 + w5) + (w6 + w7));
                numx += (w0 * g0.x + w1 * g1.x + w2 * g2.x + w3 * g3.x)
                      + (w4 * g4.x + w5 * g5.x + w6 * g6.x + w7 * g7.x);
                numy += (w0 * g0.y + w1 * g1.y + w2 * g2.y + w3 * g3.y)
                      + (w4 * g4.y + w5 * g5.y + w6 * g6.y + w7 * g7.y);
            }
            i0 += 16;
            if (i0 >= cnt) break;
            // rare tail chunks (P(cnt>16) ~ 0.2% at mean degree 6): same inline w compute
            int s_t = 0;
            if (i0 + hl < cnt) s_t = csr_s[(size_t)r * EE + stA[r] + i0 + hl];
            float x = el[(size_t)(r * Nn + s_t) * 4 + h] + erv[r];
            x = (x > 0.f) ? x : 0.2f * x;
            unsigned wb = (i0 + hl < cnt) ? (unsigned)__half_as_ushort(__float2half(__expf(x))) : 0u;
            p_l = (unsigned)s_t | (wb << 16);
        }
        float inv = 1.f / den;
        accx += numx * inv;
        accy += numy * inv;
    }
    if constexpr (OUT_BF16_RELU) {
        short* o = (short*)out;
        short2 pk;
        pk.x = f2bf(fmaxf(accx, 0.f));
        pk.y = f2bf(fmaxf(accy, 0.f));
        *(short2*)&o[(size_t)n * 128 + t2] = pk;
    } else {
        float* o = (float*)out;
        *(float2*)&o[(size_t)n * 128 + t2] = make_float2(accx, accy);
    }
}

// ---------------- launch ----------------

extern "C" void kernel_launch(void* const* d_in, const int* in_sizes, int n_in,
                              void* d_out, int out_size, void* d_ws, size_t ws_size,
                              hipStream_t stream) {
    const float* x   = (const float*)d_in[0];
    const int*  edges = (const int*)d_in[1];
    const float* W1  = (const float*)d_in[2];
    const float* al1 = (const float*)d_in[3];
    const float* ar1 = (const float*)d_in[4];
    const float* b1  = (const float*)d_in[5];
    const float* W2  = (const float*)d_in[6];
    const float* al2 = (const float*)d_in[7];
    const float* ar2 = (const float*)d_in[8];
    const float* b2  = (const float*)d_in[9];
    const float* Wl  = (const float*)d_in[10];
    const float* bl  = (const float*)d_in[11];
    float* out = (float*)d_out;

    // workspace layout (~75 MB; ws proven >= 113 MB in R2)
    __half* feat  = (__half*)d_ws;                          // 3*N*128 fp16
    short* Z      = (short*)(feat + (size_t)RR * Nn * 128); // 98304 bf16
    float* el     = (float*)(Z + 98304);                    // 3*N*4
    float* er     = el + (size_t)RR * Nn * 4;               // 3*N*4
    float* outbuf = er + (size_t)RR * Nn * 4;               // N*128 fp32 (l2) / bf16 (l1)
    int* counts    = (int*)(outbuf + (size_t)Nn * 128);     // 3*N   (contiguous with totals
    int* totals    = counts + RR * Nn;                      // 4      for single memset)
    int* row_start = totals + 4;                            // 3*N
    int* ord       = row_start + RR * Nn;                   // 3*E
    int* csr_s     = ord + RR * EE;                         // 3*E (src only)
    short* outb16  = (short*)outbuf;                        // layer-1 bf16 view

    const int rowBlocks  = (Nn + 63) / 64;    // 782
    const int nodeBlocks = (Nn + 255) / 256;  // 196
    const int aggBlocks  = (Nn + 3) / 4;      // 12500
    const int edge8Blocks = (RR * EE / 8 + 255) / 256;  // 440

    // CSR build: memset zeroes counts+totals; wswz hides under count
    hipMemsetAsync(counts, 0, (size_t)(RR * Nn + 4) * sizeof(int), stream);
    count_wswz_kernel<<<440 + 48, 256, 0, stream>>>(edges, counts, ord, W1, W2, Z);
    alloc_kernel<<<dim3(nodeBlocks, RR), 256, 0, stream>>>(counts, row_start, totals);
    scatter_kernel<<<edge8Blocks, 256, 0, stream>>>(edges, ord, row_start, csr_s);

    // layer 1 (el/er fused into gemm epilogue; w computed inline in agg; bf16+relu out)
    gemm_proj_mfma<float><<<rowBlocks, 256, 0, stream>>>(x, Z, al1, ar1, feat, el, er);
    agg_kernel<true><<<aggBlocks, 256, 0, stream>>>((const __half2*)feat, el, er, csr_s, row_start, counts, b1, outb16);

    // layer 2 (bf16 A input, relu already applied)
    gemm_proj_mfma<short><<<rowBlocks, 256, 0, stream>>>(outb16, Z + 49152, al2, ar2, feat, el, er);
    agg_kernel<false><<<aggBlocks, 256, 0, stream>>>((const __half2*)feat, el, er, csr_s, row_start, counts, b2, outbuf);

    // final linear
    gemm_final_kernel<<<rowBlocks, 256, 0, stream>>>(outbuf, Wl, bl, out);
}

// Round 15
// 306.252 us; speedup vs baseline: 1.0889x; 1.0610x over previous
//
#include <hip/hip_runtime.h>
#include <hip/hip_bf16.h>
#include <hip/hip_fp16.h>
#include <type_traits>

#define Nn 50000
#define RR 3
#define EE 300000

typedef __attribute__((ext_vector_type(8))) short short8;
typedef __attribute__((ext_vector_type(4))) short short4v;
typedef __attribute__((ext_vector_type(4))) float floatx4;

__device__ __forceinline__ short f2bf(float f) {
    __hip_bfloat16 h = __float2bfloat16(f);
    return *reinterpret_cast<short*>(&h);
}

// ---------------- count (8 edges/thread, ordinal out) + fused W1/W2/Wl pre-swizzle ----------------
// blocks [0,440): count; [440,488): W1/W2 swizzle; [488,492): Wl swizzle.
// counts pre-zeroed by hipMemsetAsync.

__global__ void count_wswz_kernel(const int* __restrict__ edges, int* __restrict__ counts,
                                  int* __restrict__ ord,
                                  const float* __restrict__ W1, const float* __restrict__ W2,
                                  const float* __restrict__ Wl, short* __restrict__ Z) {
    int bx = blockIdx.x;
    if (bx >= 488) {
        // Wl[128,64] -> B-frag layout: [kt][nt][lane][j], n=nt*16+(lane&15), k=kt*32+(lane>>4)*8+j
        int idx = (bx - 488) * 256 + threadIdx.x;   // 4kt*4nt*64 = 1024
        if (idx >= 1024) return;
        int lane = idx & 63;
        int nt = (idx >> 6) & 3;
        int kt = idx >> 8;
        int n = nt * 16 + (lane & 15);
        int k0 = kt * 32 + (lane >> 4) * 8;
        short8 v;
        #pragma unroll
        for (int j = 0; j < 8; ++j) v[j] = f2bf(Wl[(size_t)(k0 + j) * 64 + n]);
        *(short8*)&Z[98304 + (size_t)idx * 8] = v;
        return;
    }
    if (bx >= 440) {
        int idx = (bx - 440) * 256 + threadIdx.x;   // 2*3*4*8*64 = 12288
        if (idx >= 12288) return;
        int lane = idx & 63;
        int nt = (idx >> 6) & 7;
        int kt = (idx >> 9) & 3;
        int rl = idx >> 11;
        int layer = rl / 3, r = rl % 3;
        const float* W = (layer ? W2 : W1) + (size_t)r * 16384;
        int n = nt * 16 + (lane & 15);
        int k0 = kt * 32 + (lane >> 4) * 8;
        short8 v;
        #pragma unroll
        for (int j = 0; j < 8; ++j) v[j] = f2bf(W[(size_t)(k0 + j) * 128 + n]);
        *(short8*)&Z[(size_t)idx * 8] = v;
        return;
    }
    int i = bx * 256 + threadIdx.x;   // RR*EE/8 threads
    if (i >= RR * EE / 8) return;
    int g = i * 8;
    int r = g / EE, e0 = g - r * EE;
    const int* db = &edges[(size_t)r * 2 * EE + EE + e0];
    int4 d0 = *(const int4*)db;
    int4 d1 = *(const int4*)(db + 4);
    int* cb = counts + r * Nn;
    int4 o0, o1;
    o0.x = atomicAdd(&cb[d0.x], 1);
    o0.y = atomicAdd(&cb[d0.y], 1);
    o0.z = atomicAdd(&cb[d0.z], 1);
    o0.w = atomicAdd(&cb[d0.w], 1);
    o1.x = atomicAdd(&cb[d1.x], 1);
    o1.y = atomicAdd(&cb[d1.y], 1);
    o1.z = atomicAdd(&cb[d1.z], 1);
    o1.w = atomicAdd(&cb[d1.w], 1);
    *(int4*)&ord[g] = o0;
    *(int4*)&ord[g + 4] = o1;
}

__global__ __launch_bounds__(256) void alloc_kernel(const int* __restrict__ counts,
                                                    int* __restrict__ row_start,
                                                    int* __restrict__ totals) {
    __shared__ int s[256];
    __shared__ int base_s;
    int r = blockIdx.y;
    int tid = threadIdx.x;
    int n = blockIdx.x * 256 + tid;
    int idx = r * Nn + n;
    int c = (n < Nn) ? counts[idx] : 0;
    s[tid] = c;
    __syncthreads();
    #pragma unroll
    for (int off = 1; off < 256; off <<= 1) {
        int v = 0;
        if (tid >= off) v = s[tid - off];
        __syncthreads();
        if (tid >= off) s[tid] += v;
        __syncthreads();
    }
    if (tid == 255) base_s = atomicAdd(&totals[r], s[255]);
    __syncthreads();
    if (n < Nn) row_start[idx] = base_s + s[tid] - c;
}

// No atomics: slot = row_start[dst] + ord[edge]; 8 edges/thread; src-only plane.
__global__ void scatter_kernel(const int* __restrict__ edges, const int* __restrict__ ord,
                               const int* __restrict__ row_start, int* __restrict__ csr_s) {
    int i = blockIdx.x * blockDim.x + threadIdx.x;
    if (i >= RR * EE / 8) return;
    int g = i * 8;
    int r = g / EE, e0 = g - r * EE;
    const int* sb = &edges[(size_t)r * 2 * EE + e0];
    const int* db = sb + EE;
    int4 s0 = *(const int4*)sb, s1 = *(const int4*)(sb + 4);
    int4 d0 = *(const int4*)db, d1 = *(const int4*)(db + 4);
    int4 o0 = *(const int4*)&ord[g], o1 = *(const int4*)&ord[g + 4];
    const int* rs = row_start + r * Nn;
    int* cs = csr_s + (size_t)r * EE;
    cs[rs[d0.x] + o0.x] = s0.x;
    cs[rs[d0.y] + o0.y] = s0.y;
    cs[rs[d0.z] + o0.z] = s0.z;
    cs[rs[d0.w] + o0.w] = s0.w;
    cs[rs[d1.x] + o1.x] = s1.x;
    cs[rs[d1.y] + o1.y] = s1.y;
    cs[rs[d1.z] + o1.z] = s1.z;
    cs[rs[d1.w] + o1.w] = s1.w;
}

// ---------------- MFMA GEMM + fused el/er epilogue ----------------
// TA = float (layer 1) or short (layer 2, bf16 relu-applied).

template<typename TA>
__global__ __launch_bounds__(256) void gemm_proj_mfma(const TA* __restrict__ A,
                                                      const short* __restrict__ Z,
                                                      const float* __restrict__ al,
                                                      const float* __restrict__ ar,
                                                      __half* __restrict__ C,
                                                      float* __restrict__ el,
                                                      float* __restrict__ er) {
    __shared__ short A_lds[64 * 136];   // reused as __half[64*136] for the epilogue
    __shared__ float al_lds[384], ar_lds[384];
    int tid = threadIdx.x;
    int row0 = blockIdx.x * 64;
    if (tid < 128) { al_lds[256 + tid] = al[256 + tid]; ar_lds[256 + tid] = ar[256 + tid]; }
    al_lds[tid] = al[tid]; ar_lds[tid] = ar[tid];
    if constexpr (std::is_same<TA, float>::value) {
        #pragma unroll
        for (int p = 0; p < 8; ++p) {
            int f = p * 256 + tid;
            int row = f >> 5;
            int c4 = (f & 31) * 4;
            float4 v = make_float4(0.f, 0.f, 0.f, 0.f);
            if (row0 + row < Nn) v = *(const float4*)&A[(size_t)(row0 + row) * 128 + c4];
            short4v sv;
            sv[0] = f2bf(v.x); sv[1] = f2bf(v.y); sv[2] = f2bf(v.z); sv[3] = f2bf(v.w);
            *(short4v*)&A_lds[row * 136 + c4] = sv;
        }
    } else {
        #pragma unroll
        for (int p = 0; p < 4; ++p) {
            int c = p * 256 + tid;          // 1024 chunks of 8 shorts
            int row = c >> 4, c8 = (c & 15) * 8;
            short8 v = (short8)(0);
            if (row0 + row < Nn) v = *(const short8*)&A[(size_t)(row0 + row) * 128 + c8];
            *(short8*)&A_lds[row * 136 + c8] = v;
        }
    }
    __syncthreads();
    int wave = tid >> 6, lane = tid & 63;
    int m = lane & 15, q = lane >> 4;
    short8 af[4];
    #pragma unroll
    for (int kt = 0; kt < 4; ++kt)
        af[kt] = *(short8*)&A_lds[(wave * 16 + m) * 136 + kt * 32 + q * 8];
    __syncthreads();   // A_lds dead; reuse as epilogue buffer
    __half* lds_h = (__half*)A_lds;
    int row8 = tid >> 2;
    int hh = tid & 3;
    for (int r = 0; r < RR; ++r) {
        floatx4 acc[8];
        #pragma unroll
        for (int nt = 0; nt < 8; ++nt) acc[nt] = (floatx4)(0.f);
        const short* Zr = Z + (size_t)r * 16384;
        #pragma unroll
        for (int kt = 0; kt < 4; ++kt) {
            #pragma unroll
            for (int nt = 0; nt < 8; ++nt) {
                short8 bf = *(const short8*)&Zr[(size_t)(kt * 8 + nt) * 512 + lane * 8];
                acc[nt] = __builtin_amdgcn_mfma_f32_16x16x32_bf16(af[kt], bf, acc[nt], 0, 0, 0);
            }
        }
        #pragma unroll
        for (int nt = 0; nt < 8; ++nt) {
            int col = nt * 16 + m;
            #pragma unroll
            for (int reg = 0; reg < 4; ++reg)
                lds_h[(wave * 16 + q * 4 + reg) * 136 + col] = __float2half(acc[nt][reg]);
        }
        __syncthreads();
        __half* Cr = C + (size_t)r * Nn * 128;
        #pragma unroll
        for (int p = 0; p < 4; ++p) {
            int lin = p * 256 + tid;
            int row = lin >> 4, c8 = (lin & 15) * 8;
            if (row0 + row < Nn)
                *(short8*)&Cr[(size_t)(row0 + row) * 128 + c8] = *(short8*)&lds_h[row * 136 + c8];
        }
        {
            const __half2* fp = (const __half2*)&lds_h[row8 * 136 + hh * 32];
            const float* alp = &al_lds[r * 128 + hh * 32];
            const float* arp = &ar_lds[r * 128 + hh * 32];
            float sl = 0.f, sr = 0.f;
            #pragma unroll
            for (int d = 0; d < 16; ++d) {
                float2 v = __half22float2(fp[d]);
                sl += v.x * alp[2 * d] + v.y * alp[2 * d + 1];
                sr += v.x * arp[2 * d] + v.y * arp[2 * d + 1];
            }
            if (row0 + row8 < Nn) {
                size_t ei = (size_t)(r * Nn + row0 + row8) * 4 + hh;
                el[ei] = sl;
                er[ei] = sr;
            }
        }
        __syncthreads();
    }
}

// ---------------- Final GEMM (MFMA): A_bf16[N,128] @ Wl[128,64] + bl -> out fp32 [N,64] --------

__global__ __launch_bounds__(256) void final_mfma(const short* __restrict__ A,
                                                  const short* __restrict__ Zl,
                                                  const float* __restrict__ bl,
                                                  float* __restrict__ out) {
    __shared__ __align__(16) short A_lds[64 * 136];   // reused as float[64*68] epilogue buffer
    int tid = threadIdx.x;
    int row0 = blockIdx.x * 64;
    #pragma unroll
    for (int p = 0; p < 4; ++p) {
        int c = p * 256 + tid;              // 1024 chunks of 8 shorts
        int row = c >> 4, c8 = (c & 15) * 8;
        short8 v = (short8)(0);
        if (row0 + row < Nn) v = *(const short8*)&A[(size_t)(row0 + row) * 128 + c8];
        *(short8*)&A_lds[row * 136 + c8] = v;
    }
    __syncthreads();
    int wave = tid >> 6, lane = tid & 63;
    int m = lane & 15, q = lane >> 4;
    short8 af[4];
    #pragma unroll
    for (int kt = 0; kt < 4; ++kt)
        af[kt] = *(short8*)&A_lds[(wave * 16 + m) * 136 + kt * 32 + q * 8];
    __syncthreads();
    float* lds_f = (float*)A_lds;           // 64 x 68 floats (17408 B)
    floatx4 acc[4];
    #pragma unroll
    for (int nt = 0; nt < 4; ++nt) acc[nt] = (floatx4)(0.f);
    #pragma unroll
    for (int kt = 0; kt < 4; ++kt) {
        #pragma unroll
        for (int nt = 0; nt < 4; ++nt) {
            short8 bf = *(const short8*)&Zl[(size_t)(kt * 4 + nt) * 512 + lane * 8];
            acc[nt] = __builtin_amdgcn_mfma_f32_16x16x32_bf16(af[kt], bf, acc[nt], 0, 0, 0);
        }
    }
    #pragma unroll
    for (int nt = 0; nt < 4; ++nt) {
        int col = nt * 16 + m;
        #pragma unroll
        for (int reg = 0; reg < 4; ++reg)
            lds_f[(wave * 16 + q * 4 + reg) * 68 + col] = acc[nt][reg];
    }
    __syncthreads();
    #pragma unroll
    for (int p = 0; p < 4; ++p) {
        int lin = p * 256 + tid;            // 1024 float4 chunks
        int row = lin >> 4, c4 = (lin & 15) * 4;
        if (row0 + row < Nn) {
            float4 bias = *(const float4*)&bl[c4];
            float4 v = *(float4*)&lds_f[row * 68 + c4];
            v.x += bias.x; v.y += bias.y; v.z += bias.z; v.w += bias.w;
            *(float4*)&out[(size_t)(row0 + row) * 64 + c4] = v;
        }
    }
}

// ---------------- aggregation: one wave per dst node; inline (src|fp16 w) pack at chunk load --
// OUT_MODE: 1 = bf16 + relu (layer-1 -> layer-2 A), 2 = bf16 (layer-2 -> final MFMA A).

template<int OUT_MODE>
__global__ __launch_bounds__(256) void agg_kernel(const __half2* __restrict__ feat2,
                                                  const float* __restrict__ el,
                                                  const float* __restrict__ er,
                                                  const int* __restrict__ csr_s,
                                                  const int* __restrict__ row_start,
                                                  const int* __restrict__ counts,
                                                  const float* __restrict__ b,
                                                  short* __restrict__ out) {
    int wave = threadIdx.x >> 6;
    int lane = threadIdx.x & 63;
    int n = blockIdx.x * 4 + wave;
    if (n >= Nn) return;
    int h = lane >> 4;
    int hl = lane & 15;
    int grp = lane & 48;
    int t2 = lane * 2;
    int cntA[RR], stA[RR], sC[RR];
    #pragma unroll
    for (int r = 0; r < RR; ++r) {
        cntA[r] = counts[r * Nn + n];
        stA[r] = row_start[r * Nn + n];
    }
    #pragma unroll
    for (int r = 0; r < RR; ++r) {
        sC[r] = 0;
        if (hl < cntA[r]) sC[r] = csr_s[(size_t)r * EE + stA[r] + hl];
    }
    float erv[RR];
    #pragma unroll
    for (int r = 0; r < RR; ++r) erv[r] = er[(size_t)(r * Nn + n) * 4 + h];
    unsigned pC[RR];
    #pragma unroll
    for (int r = 0; r < RR; ++r) {
        float x = el[(size_t)(r * Nn + sC[r]) * 4 + h] + erv[r];
        x = (x > 0.f) ? x : 0.2f * x;
        unsigned wb = (hl < cntA[r]) ? (unsigned)__half_as_ushort(__float2half(__expf(x))) : 0u;
        pC[r] = (unsigned)sC[r] | (wb << 16);
    }
    float accx = b[t2] + b[128 + t2] + b[256 + t2];
    float accy = b[t2 + 1] + b[128 + t2 + 1] + b[256 + t2 + 1];
    #pragma unroll
    for (int r = 0; r < RR; ++r) {
        int cnt = cntA[r];
        if (cnt == 0) continue;
        const __half2* fr = feat2 + (size_t)r * Nn * 64;
        float den = 0.f, numx = 0.f, numy = 0.f;
        unsigned p_l = pC[r];
        int i0 = 0;
        while (true) {
            int mm = cnt - i0; if (mm > 16) mm = 16;
            int mm8 = (mm + 7) & ~7;
            for (int j = 0; j < mm8; j += 8) {
                unsigned u0 = __shfl(p_l, grp | j);
                unsigned u1 = __shfl(p_l, grp | (j + 1));
                unsigned u2 = __shfl(p_l, grp | (j + 2));
                unsigned u3 = __shfl(p_l, grp | (j + 3));
                unsigned u4 = __shfl(p_l, grp | (j + 4));
                unsigned u5 = __shfl(p_l, grp | (j + 5));
                unsigned u6 = __shfl(p_l, grp | (j + 6));
                unsigned u7 = __shfl(p_l, grp | (j + 7));
                __half2 f0 = fr[(size_t)(u0 & 0xFFFFu) * 64 + lane];
                __half2 f1 = fr[(size_t)(u1 & 0xFFFFu) * 64 + lane];
                __half2 f2 = fr[(size_t)(u2 & 0xFFFFu) * 64 + lane];
                __half2 f3 = fr[(size_t)(u3 & 0xFFFFu) * 64 + lane];
                __half2 f4 = fr[(size_t)(u4 & 0xFFFFu) * 64 + lane];
                __half2 f5 = fr[(size_t)(u5 & 0xFFFFu) * 64 + lane];
                __half2 f6 = fr[(size_t)(u6 & 0xFFFFu) * 64 + lane];
                __half2 f7 = fr[(size_t)(u7 & 0xFFFFu) * 64 + lane];
                float w0 = __half2float(__ushort_as_half((unsigned short)(u0 >> 16)));
                float w1 = __half2float(__ushort_as_half((unsigned short)(u1 >> 16)));
                float w2 = __half2float(__ushort_as_half((unsigned short)(u2 >> 16)));
                float w3 = __half2float(__ushort_as_half((unsigned short)(u3 >> 16)));
                float w4 = __half2float(__ushort_as_half((unsigned short)(u4 >> 16)));
                float w5 = __half2float(__ushort_as_half((unsigned short)(u5 >> 16)));
                float w6 = __half2float(__ushort_as_half((unsigned short)(u6 >> 16)));
                float w7 = __half2float(__ushort_as_half((unsigned short)(u7 >> 16)));
                float2 g0 = __half22float2(f0), g1 = __half22float2(f1);
                float2 g2 = __half22float2(f2), g3 = __half22float2(f3);
                float2 g4 = __half22float2(f4), g5 = __half22float2(f5);
                float2 g6 = __half22float2(f6), g7 = __half22float2(f7);
                den += ((w0 + w1) + (w2 + w3)) + ((w4 + w5) + (w6 + w7));
                numx += (w0 * g0.x + w1 * g1.x + w2 * g2.x + w3 * g3.x)
                      + (w4 * g4.x + w5 * g5.x + w6 * g6.x + w7 * g7.x);
                numy += (w0 * g0.y + w1 * g1.y + w2 * g2.y + w3 * g3.y)
                      + (w4 * g4.y + w5 * g5.y + w6 * g6.y + w7 * g7.y);
            }
            i0 += 16;
            if (i0 >= cnt) break;
            // rare tail chunks (P(cnt>16) ~ 0.2% at mean degree 6): same inline w compute
            int s_t = 0;
            if (i0 + hl < cnt) s_t = csr_s[(size_t)r * EE + stA[r] + i0 + hl];
            float x = el[(size_t)(r * Nn + s_t) * 4 + h] + erv[r];
            x = (x > 0.f) ? x : 0.2f * x;
            unsigned wb = (i0 + hl < cnt) ? (unsigned)__half_as_ushort(__float2half(__expf(x))) : 0u;
            p_l = (unsigned)s_t | (wb << 16);
        }
        float inv = 1.f / den;
        accx += numx * inv;
        accy += numy * inv;
    }
    short2 pk;
    if constexpr (OUT_MODE == 1) {
        pk.x = f2bf(fmaxf(accx, 0.f));
        pk.y = f2bf(fmaxf(accy, 0.f));
    } else {
        pk.x = f2bf(accx);
        pk.y = f2bf(accy);
    }
    *(short2*)&out[(size_t)n * 128 + t2] = pk;
}

// ---------------- launch ----------------

extern "C" void kernel_launch(void* const* d_in, const int* in_sizes, int n_in,
                              void* d_out, int out_size, void* d_ws, size_t ws_size,
                              hipStream_t stream) {
    const float* x   = (const float*)d_in[0];
    const int*  edges = (const int*)d_in[1];
    const float* W1  = (const float*)d_in[2];
    const float* al1 = (const float*)d_in[3];
    const float* ar1 = (const float*)d_in[4];
    const float* b1  = (const float*)d_in[5];
    const float* W2  = (const float*)d_in[6];
    const float* al2 = (const float*)d_in[7];
    const float* ar2 = (const float*)d_in[8];
    const float* b2  = (const float*)d_in[9];
    const float* Wl  = (const float*)d_in[10];
    const float* bl  = (const float*)d_in[11];
    float* out = (float*)d_out;

    // workspace layout (~70 MB; ws proven >= 113 MB in R2)
    __half* feat  = (__half*)d_ws;                          // 3*N*128 fp16
    short* Z      = (short*)(feat + (size_t)RR * Nn * 128); // 98304 (W1,W2) + 8192 (Wl) bf16
    float* el     = (float*)(Z + 106496);                   // 3*N*4
    float* er     = el + (size_t)RR * Nn * 4;               // 3*N*4
    short* outb16 = (short*)(er + (size_t)RR * Nn * 4);     // N*128 bf16 (both layers' agg out)
    int* counts    = (int*)(outb16 + (size_t)Nn * 128);     // 3*N (+4 totals, contiguous)
    int* totals    = counts + RR * Nn;                      // 4
    int* row_start = totals + 4;                            // 3*N
    int* ord       = row_start + RR * Nn;                   // 3*E
    int* csr_s     = ord + RR * EE;                         // 3*E (src only)

    const int rowBlocks  = (Nn + 63) / 64;    // 782
    const int nodeBlocks = (Nn + 255) / 256;  // 196
    const int aggBlocks  = (Nn + 3) / 4;      // 12500
    const int edge8Blocks = (RR * EE / 8 + 255) / 256;  // 440

    // CSR build: memset zeroes counts+totals; W1/W2/Wl swizzle hides under count
    hipMemsetAsync(counts, 0, (size_t)(RR * Nn + 4) * sizeof(int), stream);
    count_wswz_kernel<<<492, 256, 0, stream>>>(edges, counts, ord, W1, W2, Wl, Z);
    alloc_kernel<<<dim3(nodeBlocks, RR), 256, 0, stream>>>(counts, row_start, totals);
    scatter_kernel<<<edge8Blocks, 256, 0, stream>>>(edges, ord, row_start, csr_s);

    // layer 1 (el/er fused into gemm epilogue; w computed inline in agg; bf16+relu out)
    gemm_proj_mfma<float><<<rowBlocks, 256, 0, stream>>>(x, Z, al1, ar1, feat, el, er);
    agg_kernel<1><<<aggBlocks, 256, 0, stream>>>((const __half2*)feat, el, er, csr_s, row_start, counts, b1, outb16);

    // layer 2 (bf16 A input, relu already applied; agg writes bf16 for the MFMA final)
    gemm_proj_mfma<short><<<rowBlocks, 256, 0, stream>>>(outb16, Z + 49152, al2, ar2, feat, el, er);
    agg_kernel<2><<<aggBlocks, 256, 0, stream>>>((const __half2*)feat, el, er, csr_s, row_start, counts, b2, outb16);

    // final linear (MFMA, bf16 A, pre-swizzled Wl)
    final_mfma<<<rowBlocks, 256, 0, stream>>>(outb16, Z + 98304, bl, out);
}